// Round 11
// baseline (134.001 us; speedup 1.0000x reference)
//
#include <hip/hip_runtime.h>
#include <hip/hip_fp16.h>
#include <hip/hip_bf16.h>

#define B_ 256
#define D_ 1024
#define N_ 200000
#define K_ 64
#define EXPNEG24_ 3.7751345e-11f  // e^-24, folded into priority at stage time
#define NCHUNK 3125   // N_/64 exactly
#define SL_ 8         // (legacy) G alignment

typedef short short8 __attribute__((ext_vector_type(8)));
typedef _Float16 f16x8 __attribute__((ext_vector_type(8)));
typedef float f32x4 __attribute__((ext_vector_type(4)));

__device__ __forceinline__ unsigned f2bf(float x) {
  unsigned u = __float_as_uint(x);
  return (u + 0x7fffu + ((u >> 16) & 1u)) >> 16;
}
// packed f32x2 -> bf16x2 (RNE); compiler lowers to v_cvt_pk_bf16_f32.
// (__hip_bfloat162 is not trivially copyable -> bits via __builtin_memcpy)
__device__ __forceinline__ unsigned pkbf(float a, float b) {
  __hip_bfloat162 h = __float22bfloat162_rn(make_float2(a, b));
  unsigned r;
  __builtin_memcpy(&r, &h, sizeof(r));
  return r;
}
__device__ __forceinline__ unsigned f2h(float x) {  // fp16 bits, RNE
  return (unsigned)__half_as_ushort(__float2half(x));
}
__device__ __forceinline__ f32x4 mfma16b(int4 a, int4 b, f32x4 c) {  // bf16
  return __builtin_amdgcn_mfma_f32_16x16x32_bf16(
      __builtin_bit_cast(short8, a), __builtin_bit_cast(short8, b), c, 0, 0, 0);
}
__device__ __forceinline__ f32x4 mfma16h(int4 a, int4 b, f32x4 c) {  // fp16
  return __builtin_amdgcn_mfma_f32_16x16x32_f16(
      __builtin_bit_cast(f16x8, a), __builtin_bit_cast(f16x8, b), c, 0, 0, 0);
}
__device__ __forceinline__ int p8hash(int k) { return ((k >> 3) ^ k) & 7; }

// ---------------------------------------------------------------------------
// K1: cue_outer[b][k] = sum_d cue[b][d] * w_cue[k][d]  (frozen)
// ---------------------------------------------------------------------------
__global__ __launch_bounds__(256) void k1_cueproj(
    const float* __restrict__ cue, const float* __restrict__ wcue,
    float* __restrict__ couter) {
  const int b    = blockIdx.x;
  const int tid  = threadIdx.x;
  const int w    = tid >> 6;
  const int lane = tid & 63;

  __shared__ float part[4][64][65];
  __shared__ float red[4][64];

  const float4 creg =
      *(const float4*)(cue + (size_t)b * D_ + w * 256 + lane * 4);
  const float* wbase = wcue + w * 256 + lane * 4;

#pragma unroll 8
  for (int k = 0; k < 64; ++k) {
    const float4 wv = *(const float4*)(wbase + (size_t)k * D_);
    part[w][k][lane] =
        creg.x * wv.x + creg.y * wv.y + creg.z * wv.z + creg.w * wv.w;
  }
  __syncthreads();

  const int k  = tid & 63;
  const int wq = tid >> 6;
  float a = 0.f;
#pragma unroll 8
  for (int j = 0; j < 64; ++j) a += part[wq][k][j];
  red[wq][k] = a;
  __syncthreads();
  if (tid < 64) {
    couter[b * K_ + tid] =
        red[0][tid] + red[1][tid] + red[2][tid] + red[3][tid];
  }
}

// ---------------------------------------------------------------------------
// K2: MFMA flash-attention. Round-8 verified kernel (3-phase, register-
// resident E via k-permutation, overlapped sh_T scatter; setprio removed —
// measured neutral/negative at R10). This round's single lever: grid
// G=1024 -> 4 blocks/CU (was grid-limited to 2). Resource check:
// VGPR 128 -> 4 waves/SIMD; LDS 36.9KB x4 = 147.6 <= 160 KB. Total
// chunk-work invariant in G (each block owns ~3 chunks instead of ~6);
// independent co-resident blocks overlap GEMM phases with barrier/stage
// phases of their neighbors.
// ---------------------------------------------------------------------------
__global__ __launch_bounds__(256, 2) void k2_attend(
    const float* __restrict__ slot, const float* __restrict__ prio,
    const float* __restrict__ couter, unsigned short* __restrict__ Spart,
    float* __restrict__ Zpart, int G) {
  // live union: sh_h[64*72] | sh_T[64*64] | sh_p[64]f  = 17.7 KB
  // epilogue overlay view: [4][64][72] shorts = 36864 B (sizes the array)
  __shared__ __align__(16) unsigned short sh_all[18432];
  unsigned short* const sh_h = sh_all;          // 4608 shorts
  unsigned short* const sh_T = sh_all + 4608;   // 4096 shorts
  float* const sh_p = (float*)(sh_all + 8704);  // 64 floats

  const int tid = threadIdx.x;
  const int g   = blockIdx.x;
  const int l   = tid & 63;
  const int w   = tid >> 6;
  const int c16 = l & 15;
  const int q   = l >> 4;

  // Q fragments (fp16), loaded once
  int4 qf[4][2];
#pragma unroll
  for (int bt = 0; bt < 4; ++bt) {
#pragma unroll
    for (int s = 0; s < 2; ++s) {
      const float* qp =
          couter + (size_t)(w * 64 + bt * 16 + c16) * K_ + s * 32 + q * 8;
      float4 va = *(const float4*)qp;
      float4 vb = *(const float4*)(qp + 4);
      qf[bt][s] = make_int4(
          (int)(f2h(va.x) | (f2h(va.y) << 16)),
          (int)(f2h(va.z) | (f2h(va.w) << 16)),
          (int)(f2h(vb.x) | (f2h(vb.y) << 16)),
          (int)(f2h(vb.z) | (f2h(vb.w) << 16)));
    }
  }

  f32x4 S[4][4];
#pragma unroll
  for (int a = 0; a < 4; ++a)
#pragma unroll
    for (int b = 0; b < 4; ++b) S[a][b] = (f32x4){0.f, 0.f, 0.f, 0.f};
  float zacc[4] = {0.f, 0.f, 0.f, 0.f};

  // prefetch chunk g
  float4 pf[4];
  float ppf = 0.f;
  {
    const float4* src = (const float4*)(slot + (size_t)g * 64 * K_);
#pragma unroll
    for (int i = 0; i < 4; ++i) pf[i] = src[tid + 256 * i];
    if (tid < 64) ppf = prio[g * 64 + tid];
  }

  for (int chunk = g; chunk < NCHUNK; chunk += G) {
    __syncthreads();  // b1: previous GEMM2 reads done, buffers reusable
    // ---- phase1: sh_h (fp16 row-major, pad 72) + sh_p ----
#pragma unroll
    for (int i = 0; i < 4; ++i) {
      const int f   = tid + 256 * i;
      const int row = f >> 4;
      const int c4  = (f & 15) * 4;
      *(uint2*)&sh_h[row * 72 + c4] =
          make_uint2(f2h(pf[i].x) | (f2h(pf[i].y) << 16),
                     f2h(pf[i].z) | (f2h(pf[i].w) << 16));
    }
    if (tid < 64) sh_p[tid] = ppf * EXPNEG24_;  // fold exp(-24) into prio
    __syncthreads();  // b2: sh_h/sh_p ready

    // ---- phase2: sh_T scatter (overlaps GEMM1) ----
#pragma unroll
    for (int i = 0; i < 4; ++i) {
      const int f   = tid + 256 * i;
      const int row = f >> 4;
      const int c4  = (f & 15) * 4;
      const unsigned t01 = pkbf(pf[i].x, pf[i].y);
      const unsigned t23 = pkbf(pf[i].z, pf[i].w);
      sh_T[(c4 + 0) * 64 + (row ^ (p8hash(c4 + 0) << 3))] =
          (unsigned short)t01;
      sh_T[(c4 + 1) * 64 + (row ^ (p8hash(c4 + 1) << 3))] =
          (unsigned short)(t01 >> 16);
      sh_T[(c4 + 2) * 64 + (row ^ (p8hash(c4 + 2) << 3))] =
          (unsigned short)t23;
      sh_T[(c4 + 3) * 64 + (row ^ (p8hash(c4 + 3) << 3))] =
          (unsigned short)(t23 >> 16);
    }
    // ---- prefetch next chunk (after pf's last use above) ----
    const int nxt = chunk + G;
    if (nxt < NCHUNK) {
      const float4* src = (const float4*)(slot + (size_t)nxt * 64 * K_);
#pragma unroll
      for (int i = 0; i < 4; ++i) pf[i] = src[tid + 256 * i];
      if (tid < 64) ppf = prio[nxt * 64 + tid];
    }

    // ---- GEMM1 all 4 tiles -> E in registers (both halves) ----
    int P[4][8];  // per bt: 8 bf16x2 words, k-slot pi-ordered, both halves
#pragma unroll
    for (int t = 0; t < 4; ++t) {
      f32x4 cc[4];
#pragma unroll
      for (int bt = 0; bt < 4; ++bt) cc[bt] = (f32x4){0.f, 0.f, 0.f, 0.f};
#pragma unroll
      for (int s = 0; s < 2; ++s) {
        const int off = (t * 16 + c16) * 72 + s * 32 + q * 8;
        int4 ah = *(const int4*)&sh_h[off];
#pragma unroll
        for (int bt = 0; bt < 4; ++bt)
          cc[bt] = mfma16h(ah, qf[bt][s], cc[bt]);
      }
      const float4 p = *(const float4*)&sh_p[t * 16 + q * 4];
#pragma unroll
      for (int bt = 0; bt < 4; ++bt) {
        float e0 = __expf(cc[bt][0]) * p.x;
        float e1 = __expf(cc[bt][1]) * p.y;
        float e2 = __expf(cc[bt][2]) * p.z;
        float e3 = __expf(cc[bt][3]) * p.w;
        zacc[bt] += (e0 + e1) + (e2 + e3);
        P[bt][t * 2 + 0] = (int)pkbf(e0, e1);
        P[bt][t * 2 + 1] = (int)pkbf(e2, e3);
      }
    }
    __syncthreads();  // b3: sh_T complete across all waves

    // ---- phase3: GEMM2 both halves (A=slotT from sh_T, B=E from regs) ----
#pragma unroll
    for (int h = 0; h < 2; ++h) {
      // k-slots q*8+0..3 -> n = h*32+q*4+0..3 ; q*8+4..7 -> n = h*32+16+q*4+..
      int4 bA[4];
#pragma unroll
      for (int ct = 0; ct < 4; ++ct) {
        const int k  = ct * 16 + c16;
        const int sw = p8hash(k) << 3;
        int2 t0 = *(const int2*)&sh_T[k * 64 + ((h * 32 + q * 4) ^ sw)];
        int2 t1 = *(const int2*)&sh_T[k * 64 + ((h * 32 + 16 + q * 4) ^ sw)];
        bA[ct] = make_int4(t0.x, t0.y, t1.x, t1.y);
      }
#pragma unroll
      for (int bt = 0; bt < 4; ++bt) {
        const int4 Pb = make_int4(P[bt][4 * h + 0], P[bt][4 * h + 1],
                                  P[bt][4 * h + 2], P[bt][4 * h + 3]);
#pragma unroll
        for (int ct = 0; ct < 4; ++ct)
          S[bt][ct] = mfma16b(bA[ct], Pb, S[bt][ct]);
      }
    }
  }

  // ---- epilogue: S (row=kout=ct*16+q*4+r, col=batch=bt*16+c16) ----
  __syncthreads();  // all chunk compute done; sh_all reusable
  unsigned short* const stg = sh_all;
#pragma unroll
  for (int bt = 0; bt < 4; ++bt) {
#pragma unroll
    for (int ct = 0; ct < 4; ++ct) {
      uint2 v = make_uint2(pkbf(S[bt][ct][0], S[bt][ct][1]),
                           pkbf(S[bt][ct][2], S[bt][ct][3]));
      *(uint2*)&stg[(w * 64 + bt * 16 + c16) * 72 + ct * 16 + q * 4] = v;
    }
  }
  __syncthreads();
#pragma unroll
  for (int i = 0; i < 8; ++i) {
    const int idx   = tid + 256 * i;
    const int batch = idx >> 3;
    const int seg   = idx & 7;
    uint4 v = *(const uint4*)&stg[batch * 72 + seg * 8];
    *(uint4*)&Spart[((size_t)batch * G + g) * K_ + seg * 8] = v;
  }
#pragma unroll
  for (int bt = 0; bt < 4; ++bt) {
    float z = zacc[bt];
    z += __shfl_xor(z, 16);
    z += __shfl_xor(z, 32);
    if (l < 16) Zpart[(size_t)(w * 64 + bt * 16 + c16) * G + g] = z;
  }
}

// ---------------------------------------------------------------------------
// K3 (fused, round-8 verified form): per batch b — Z tree-reduce, Spart
// reduce -> rk, decode via LDS-staged wdec tiles (coalesced global reads).
// G-dependent loops handle G=1024 (reduce range doubles, ~+2.5 us).
// ---------------------------------------------------------------------------
__global__ __launch_bounds__(256) void k3_fused(
    const unsigned short* __restrict__ Spart, const float* __restrict__ Zpart,
    const float* __restrict__ wdec, float* __restrict__ out, int G) {
  const int b   = blockIdx.x;
  const int tid = threadIdx.x;
  const int w   = tid >> 6;
  const int l   = tid & 63;

  __shared__ float part[32][65];
  __shared__ float rk[K_];
  __shared__ float zred[4];
  __shared__ float wlds[256 * 65];

  // Z: tree-reduce Zpart[b][0..G)
  float zp = 0.f;
  const float* zpp = Zpart + (size_t)b * G;
  for (int gg = tid; gg < G; gg += 256) zp += zpp[gg];
#pragma unroll
  for (int s = 1; s < 64; s <<= 1) zp += __shfl_xor(zp, s);
  if (l == 0) zred[w] = zp;

  // rk: reduce Spart[b] (G x 64 bf16)
  const int gq = tid >> 3;
  const int k8 = tid & 7;
  float acc[8] = {0.f, 0.f, 0.f, 0.f, 0.f, 0.f, 0.f, 0.f};
  const unsigned short* sp = Spart + (size_t)b * G * K_ + k8 * 8;
  for (int gg = gq; gg < G; gg += 32) {
    uint4 v = *(const uint4*)(sp + (size_t)gg * K_);
    acc[0] += __uint_as_float(v.x << 16);
    acc[1] += __uint_as_float(v.x & 0xffff0000u);
    acc[2] += __uint_as_float(v.y << 16);
    acc[3] += __uint_as_float(v.y & 0xffff0000u);
    acc[4] += __uint_as_float(v.z << 16);
    acc[5] += __uint_as_float(v.z & 0xffff0000u);
    acc[6] += __uint_as_float(v.w << 16);
    acc[7] += __uint_as_float(v.w & 0xffff0000u);
  }
#pragma unroll
  for (int j = 0; j < 8; ++j) part[gq][k8 * 8 + j] = acc[j];
  __syncthreads();
  if (tid < 64) {
    float sum = 0.f;
#pragma unroll
    for (int r = 0; r < 32; ++r) sum += part[r][tid];
    rk[tid] = sum;
  }
  if (tid == 0)
    zred[0] = fmaxf(zred[0] + zred[1] + zred[2] + zred[3], 1e-30f);
  __syncthreads();
  const float invZ = 1.0f / zred[0];

  // decode: 4 tiles of 256 rows of wdec
  for (int j = 0; j < 4; ++j) {
#pragma unroll
    for (int i = 0; i < 16; ++i) {
      const int f   = tid + 256 * i;
      const int row = f >> 4;
      const int c4  = (f & 15) * 4;
      const float4 v =
          *(const float4*)(wdec + (size_t)(j * 256 + row) * K_ + c4);
      wlds[row * 65 + c4 + 0] = v.x;
      wlds[row * 65 + c4 + 1] = v.y;
      wlds[row * 65 + c4 + 2] = v.z;
      wlds[row * 65 + c4 + 3] = v.w;
    }
    __syncthreads();
    float acc2 = 0.f;
#pragma unroll
    for (int kk = 0; kk < 64; ++kk) acc2 += rk[kk] * wlds[tid * 65 + kk];
    out[(size_t)b * D_ + j * 256 + tid] = acc2 * invZ;
    __syncthreads();
  }
}

// ---------------------------------------------------------------------------
extern "C" void kernel_launch(void* const* d_in, const int* in_sizes, int n_in,
                              void* d_out, int out_size, void* d_ws,
                              size_t ws_size, hipStream_t stream) {
  const float* cue  = (const float*)d_in[0];
  const float* slot = (const float*)d_in[1];
  const float* prio = (const float*)d_in[2];
  const float* wcue = (const float*)d_in[3];
  const float* wdec = (const float*)d_in[4];
  float* out = (float*)d_out;

  // ws: couter (64KB) | Spart bf16 [B][G][64] | Zpart fp32 [B][G]
  const size_t per_g = (size_t)B_ * K_ * 2 + (size_t)B_ * 4;  // 33792 B
  long long avail = (long long)ws_size - 65536 - 524288;
  int G = (int)(avail > 0 ? avail / (long long)per_g : SL_);
  if (G > 1024) G = 1024;   // 4 blocks/CU (was 512 = 2); 33.6MB Spart
  G &= ~(SL_ - 1);
  if (G < SL_) G = SL_;

  float* couter         = (float*)d_ws;
  unsigned short* Spart = (unsigned short*)(couter + 16384);
  float* Zpart          = (float*)(Spart + (size_t)B_ * G * K_);

  k1_cueproj<<<dim3(B_), dim3(256), 0, stream>>>(cue, wcue, couter);
  k2_attend<<<dim3(G), dim3(256), 0, stream>>>(slot, prio, couter, Spart,
                                               Zpart, G);
  k3_fused<<<dim3(B_), dim3(256), 0, stream>>>(Spart, Zpart, wdec, out, G);
}

// Round 12
// 126.238 us; speedup vs baseline: 1.0615x; 1.0615x over previous
//
#include <hip/hip_runtime.h>
#include <hip/hip_fp16.h>
#include <hip/hip_bf16.h>

#define B_ 256
#define D_ 1024
#define N_ 200000
#define K_ 64
#define EXPNEG24_ 3.7751345e-11f  // e^-24, folded into priority at stage time
#define NCHUNK 3125   // N_/64 exactly
#define SL_ 8         // (legacy) G alignment

typedef short short8 __attribute__((ext_vector_type(8)));
typedef _Float16 f16x8 __attribute__((ext_vector_type(8)));
typedef float f32x4 __attribute__((ext_vector_type(4)));

__device__ __forceinline__ unsigned f2bf(float x) {
  unsigned u = __float_as_uint(x);
  return (u + 0x7fffu + ((u >> 16) & 1u)) >> 16;
}
// packed f32x2 -> bf16x2 (RNE); compiler lowers to v_cvt_pk_bf16_f32.
// (__hip_bfloat162 is not trivially copyable -> bits via __builtin_memcpy)
__device__ __forceinline__ unsigned pkbf(float a, float b) {
  __hip_bfloat162 h = __float22bfloat162_rn(make_float2(a, b));
  unsigned r;
  __builtin_memcpy(&r, &h, sizeof(r));
  return r;
}
__device__ __forceinline__ unsigned f2h(float x) {  // fp16 bits, RNE
  return (unsigned)__half_as_ushort(__float2half(x));
}
__device__ __forceinline__ f32x4 mfma16b(int4 a, int4 b, f32x4 c) {  // bf16
  return __builtin_amdgcn_mfma_f32_16x16x32_bf16(
      __builtin_bit_cast(short8, a), __builtin_bit_cast(short8, b), c, 0, 0, 0);
}
__device__ __forceinline__ f32x4 mfma16h(int4 a, int4 b, f32x4 c) {  // fp16
  return __builtin_amdgcn_mfma_f32_16x16x32_f16(
      __builtin_bit_cast(f16x8, a), __builtin_bit_cast(f16x8, b), c, 0, 0, 0);
}
__device__ __forceinline__ int p8hash(int k) { return ((k >> 3) ^ k) & 7; }

// ---------------------------------------------------------------------------
// K1: cue_outer[b][k] = sum_d cue[b][d] * w_cue[k][d]  (frozen)
// ---------------------------------------------------------------------------
__global__ __launch_bounds__(256) void k1_cueproj(
    const float* __restrict__ cue, const float* __restrict__ wcue,
    float* __restrict__ couter) {
  const int b    = blockIdx.x;
  const int tid  = threadIdx.x;
  const int w    = tid >> 6;
  const int lane = tid & 63;

  __shared__ float part[4][64][65];
  __shared__ float red[4][64];

  const float4 creg =
      *(const float4*)(cue + (size_t)b * D_ + w * 256 + lane * 4);
  const float* wbase = wcue + w * 256 + lane * 4;

#pragma unroll 8
  for (int k = 0; k < 64; ++k) {
    const float4 wv = *(const float4*)(wbase + (size_t)k * D_);
    part[w][k][lane] =
        creg.x * wv.x + creg.y * wv.y + creg.z * wv.z + creg.w * wv.w;
  }
  __syncthreads();

  const int k  = tid & 63;
  const int wq = tid >> 6;
  float a = 0.f;
#pragma unroll 8
  for (int j = 0; j < 64; ++j) a += part[wq][k][j];
  red[wq][k] = a;
  __syncthreads();
  if (tid < 64) {
    couter[b * K_ + tid] =
        red[0][tid] + red[1][tid] + red[2][tid] + red[3][tid];
  }
}

// ---------------------------------------------------------------------------
// K2: MFMA flash-attention — the round-8 verified optimum (125.7 us total):
// 3-phase chunk loop (sh_h stage | sh_T scatter overlapped with GEMM1 ->
// E register-resident via k-permutation | GEMM2), G=512 (2 blocks/CU).
// Dead levers, measured: atomics (R1 +24us), dbuf/1-barrier (R2 ~0),
// 8-wave block (R3 +14us), setprio (R10 +2us), G=1024 (R11 +8us).
// ---------------------------------------------------------------------------
__global__ __launch_bounds__(256, 2) void k2_attend(
    const float* __restrict__ slot, const float* __restrict__ prio,
    const float* __restrict__ couter, unsigned short* __restrict__ Spart,
    float* __restrict__ Zpart, int G) {
  // live union: sh_h[64*72] | sh_T[64*64] | sh_p[64]f  = 17.7 KB
  // epilogue overlay view: [4][64][72] shorts = 36864 B (sizes the array)
  __shared__ __align__(16) unsigned short sh_all[18432];
  unsigned short* const sh_h = sh_all;          // 4608 shorts
  unsigned short* const sh_T = sh_all + 4608;   // 4096 shorts
  float* const sh_p = (float*)(sh_all + 8704);  // 64 floats

  const int tid = threadIdx.x;
  const int g   = blockIdx.x;
  const int l   = tid & 63;
  const int w   = tid >> 6;
  const int c16 = l & 15;
  const int q   = l >> 4;

  // Q fragments (fp16), loaded once
  int4 qf[4][2];
#pragma unroll
  for (int bt = 0; bt < 4; ++bt) {
#pragma unroll
    for (int s = 0; s < 2; ++s) {
      const float* qp =
          couter + (size_t)(w * 64 + bt * 16 + c16) * K_ + s * 32 + q * 8;
      float4 va = *(const float4*)qp;
      float4 vb = *(const float4*)(qp + 4);
      qf[bt][s] = make_int4(
          (int)(f2h(va.x) | (f2h(va.y) << 16)),
          (int)(f2h(va.z) | (f2h(va.w) << 16)),
          (int)(f2h(vb.x) | (f2h(vb.y) << 16)),
          (int)(f2h(vb.z) | (f2h(vb.w) << 16)));
    }
  }

  f32x4 S[4][4];
#pragma unroll
  for (int a = 0; a < 4; ++a)
#pragma unroll
    for (int b = 0; b < 4; ++b) S[a][b] = (f32x4){0.f, 0.f, 0.f, 0.f};
  float zacc[4] = {0.f, 0.f, 0.f, 0.f};

  // prefetch chunk g
  float4 pf[4];
  float ppf = 0.f;
  {
    const float4* src = (const float4*)(slot + (size_t)g * 64 * K_);
#pragma unroll
    for (int i = 0; i < 4; ++i) pf[i] = src[tid + 256 * i];
    if (tid < 64) ppf = prio[g * 64 + tid];
  }

  for (int chunk = g; chunk < NCHUNK; chunk += G) {
    __syncthreads();  // b1: previous GEMM2 reads done, buffers reusable
    // ---- phase1: sh_h (fp16 row-major, pad 72) + sh_p ----
#pragma unroll
    for (int i = 0; i < 4; ++i) {
      const int f   = tid + 256 * i;
      const int row = f >> 4;
      const int c4  = (f & 15) * 4;
      *(uint2*)&sh_h[row * 72 + c4] =
          make_uint2(f2h(pf[i].x) | (f2h(pf[i].y) << 16),
                     f2h(pf[i].z) | (f2h(pf[i].w) << 16));
    }
    if (tid < 64) sh_p[tid] = ppf * EXPNEG24_;  // fold exp(-24) into prio
    __syncthreads();  // b2: sh_h/sh_p ready

    // ---- phase2: sh_T scatter (overlaps GEMM1) ----
#pragma unroll
    for (int i = 0; i < 4; ++i) {
      const int f   = tid + 256 * i;
      const int row = f >> 4;
      const int c4  = (f & 15) * 4;
      const unsigned t01 = pkbf(pf[i].x, pf[i].y);
      const unsigned t23 = pkbf(pf[i].z, pf[i].w);
      sh_T[(c4 + 0) * 64 + (row ^ (p8hash(c4 + 0) << 3))] =
          (unsigned short)t01;
      sh_T[(c4 + 1) * 64 + (row ^ (p8hash(c4 + 1) << 3))] =
          (unsigned short)(t01 >> 16);
      sh_T[(c4 + 2) * 64 + (row ^ (p8hash(c4 + 2) << 3))] =
          (unsigned short)t23;
      sh_T[(c4 + 3) * 64 + (row ^ (p8hash(c4 + 3) << 3))] =
          (unsigned short)(t23 >> 16);
    }
    // ---- prefetch next chunk (after pf's last use above) ----
    const int nxt = chunk + G;
    if (nxt < NCHUNK) {
      const float4* src = (const float4*)(slot + (size_t)nxt * 64 * K_);
#pragma unroll
      for (int i = 0; i < 4; ++i) pf[i] = src[tid + 256 * i];
      if (tid < 64) ppf = prio[nxt * 64 + tid];
    }

    // ---- GEMM1 all 4 tiles -> E in registers (both halves) ----
    int P[4][8];  // per bt: 8 bf16x2 words, k-slot pi-ordered, both halves
#pragma unroll
    for (int t = 0; t < 4; ++t) {
      f32x4 cc[4];
#pragma unroll
      for (int bt = 0; bt < 4; ++bt) cc[bt] = (f32x4){0.f, 0.f, 0.f, 0.f};
#pragma unroll
      for (int s = 0; s < 2; ++s) {
        const int off = (t * 16 + c16) * 72 + s * 32 + q * 8;
        int4 ah = *(const int4*)&sh_h[off];
#pragma unroll
        for (int bt = 0; bt < 4; ++bt)
          cc[bt] = mfma16h(ah, qf[bt][s], cc[bt]);
      }
      const float4 p = *(const float4*)&sh_p[t * 16 + q * 4];
#pragma unroll
      for (int bt = 0; bt < 4; ++bt) {
        float e0 = __expf(cc[bt][0]) * p.x;
        float e1 = __expf(cc[bt][1]) * p.y;
        float e2 = __expf(cc[bt][2]) * p.z;
        float e3 = __expf(cc[bt][3]) * p.w;
        zacc[bt] += (e0 + e1) + (e2 + e3);
        P[bt][t * 2 + 0] = (int)pkbf(e0, e1);
        P[bt][t * 2 + 1] = (int)pkbf(e2, e3);
      }
    }
    __syncthreads();  // b3: sh_T complete across all waves

    // ---- phase3: GEMM2 both halves (A=slotT from sh_T, B=E from regs) ----
#pragma unroll
    for (int h = 0; h < 2; ++h) {
      // k-slots q*8+0..3 -> n = h*32+q*4+0..3 ; q*8+4..7 -> n = h*32+16+q*4+..
      int4 bA[4];
#pragma unroll
      for (int ct = 0; ct < 4; ++ct) {
        const int k  = ct * 16 + c16;
        const int sw = p8hash(k) << 3;
        int2 t0 = *(const int2*)&sh_T[k * 64 + ((h * 32 + q * 4) ^ sw)];
        int2 t1 = *(const int2*)&sh_T[k * 64 + ((h * 32 + 16 + q * 4) ^ sw)];
        bA[ct] = make_int4(t0.x, t0.y, t1.x, t1.y);
      }
#pragma unroll
      for (int bt = 0; bt < 4; ++bt) {
        const int4 Pb = make_int4(P[bt][4 * h + 0], P[bt][4 * h + 1],
                                  P[bt][4 * h + 2], P[bt][4 * h + 3]);
#pragma unroll
        for (int ct = 0; ct < 4; ++ct)
          S[bt][ct] = mfma16b(bA[ct], Pb, S[bt][ct]);
      }
    }
  }

  // ---- epilogue: S (row=kout=ct*16+q*4+r, col=batch=bt*16+c16) ----
  __syncthreads();  // all chunk compute done; sh_all reusable
  unsigned short* const stg = sh_all;
#pragma unroll
  for (int bt = 0; bt < 4; ++bt) {
#pragma unroll
    for (int ct = 0; ct < 4; ++ct) {
      uint2 v = make_uint2(pkbf(S[bt][ct][0], S[bt][ct][1]),
                           pkbf(S[bt][ct][2], S[bt][ct][3]));
      *(uint2*)&stg[(w * 64 + bt * 16 + c16) * 72 + ct * 16 + q * 4] = v;
    }
  }
  __syncthreads();
#pragma unroll
  for (int i = 0; i < 8; ++i) {
    const int idx   = tid + 256 * i;
    const int batch = idx >> 3;
    const int seg   = idx & 7;
    uint4 v = *(const uint4*)&stg[batch * 72 + seg * 8];
    *(uint4*)&Spart[((size_t)batch * G + g) * K_ + seg * 8] = v;
  }
#pragma unroll
  for (int bt = 0; bt < 4; ++bt) {
    float z = zacc[bt];
    z += __shfl_xor(z, 16);
    z += __shfl_xor(z, 32);
    if (l < 16) Zpart[(size_t)(w * 64 + bt * 16 + c16) * G + g] = z;
  }
}

// ---------------------------------------------------------------------------
// K3 (fused, round-8 verified form): per batch b — Z tree-reduce, Spart
// reduce -> rk, decode via LDS-staged wdec tiles (coalesced global reads;
// direct per-row reads are stride-256B across lanes = uncoalesced, R9 -10us).
// ---------------------------------------------------------------------------
__global__ __launch_bounds__(256) void k3_fused(
    const unsigned short* __restrict__ Spart, const float* __restrict__ Zpart,
    const float* __restrict__ wdec, float* __restrict__ out, int G) {
  const int b   = blockIdx.x;
  const int tid = threadIdx.x;
  const int w   = tid >> 6;
  const int l   = tid & 63;

  __shared__ float part[32][65];
  __shared__ float rk[K_];
  __shared__ float zred[4];
  __shared__ float wlds[256 * 65];

  // Z: tree-reduce Zpart[b][0..G)
  float zp = 0.f;
  const float* zpp = Zpart + (size_t)b * G;
  for (int gg = tid; gg < G; gg += 256) zp += zpp[gg];
#pragma unroll
  for (int s = 1; s < 64; s <<= 1) zp += __shfl_xor(zp, s);
  if (l == 0) zred[w] = zp;

  // rk: reduce Spart[b] (G x 64 bf16)
  const int gq = tid >> 3;
  const int k8 = tid & 7;
  float acc[8] = {0.f, 0.f, 0.f, 0.f, 0.f, 0.f, 0.f, 0.f};
  const unsigned short* sp = Spart + (size_t)b * G * K_ + k8 * 8;
  for (int gg = gq; gg < G; gg += 32) {
    uint4 v = *(const uint4*)(sp + (size_t)gg * K_);
    acc[0] += __uint_as_float(v.x << 16);
    acc[1] += __uint_as_float(v.x & 0xffff0000u);
    acc[2] += __uint_as_float(v.y << 16);
    acc[3] += __uint_as_float(v.y & 0xffff0000u);
    acc[4] += __uint_as_float(v.z << 16);
    acc[5] += __uint_as_float(v.z & 0xffff0000u);
    acc[6] += __uint_as_float(v.w << 16);
    acc[7] += __uint_as_float(v.w & 0xffff0000u);
  }
#pragma unroll
  for (int j = 0; j < 8; ++j) part[gq][k8 * 8 + j] = acc[j];
  __syncthreads();
  if (tid < 64) {
    float sum = 0.f;
#pragma unroll
    for (int r = 0; r < 32; ++r) sum += part[r][tid];
    rk[tid] = sum;
  }
  if (tid == 0)
    zred[0] = fmaxf(zred[0] + zred[1] + zred[2] + zred[3], 1e-30f);
  __syncthreads();
  const float invZ = 1.0f / zred[0];

  // decode: 4 tiles of 256 rows of wdec
  for (int j = 0; j < 4; ++j) {
#pragma unroll
    for (int i = 0; i < 16; ++i) {
      const int f   = tid + 256 * i;
      const int row = f >> 4;
      const int c4  = (f & 15) * 4;
      const float4 v =
          *(const float4*)(wdec + (size_t)(j * 256 + row) * K_ + c4);
      wlds[row * 65 + c4 + 0] = v.x;
      wlds[row * 65 + c4 + 1] = v.y;
      wlds[row * 65 + c4 + 2] = v.z;
      wlds[row * 65 + c4 + 3] = v.w;
    }
    __syncthreads();
    float acc2 = 0.f;
#pragma unroll
    for (int kk = 0; kk < 64; ++kk) acc2 += rk[kk] * wlds[tid * 65 + kk];
    out[(size_t)b * D_ + j * 256 + tid] = acc2 * invZ;
    __syncthreads();
  }
}

// ---------------------------------------------------------------------------
extern "C" void kernel_launch(void* const* d_in, const int* in_sizes, int n_in,
                              void* d_out, int out_size, void* d_ws,
                              size_t ws_size, hipStream_t stream) {
  const float* cue  = (const float*)d_in[0];
  const float* slot = (const float*)d_in[1];
  const float* prio = (const float*)d_in[2];
  const float* wcue = (const float*)d_in[3];
  const float* wdec = (const float*)d_in[4];
  float* out = (float*)d_out;

  // ws: couter (64KB) | Spart bf16 [B][G][64] | Zpart fp32 [B][G]
  const size_t per_g = (size_t)B_ * K_ * 2 + (size_t)B_ * 4;  // 33792 B
  long long avail = (long long)ws_size - 65536 - 524288;
  int G = (int)(avail > 0 ? avail / (long long)per_g : SL_);
  if (G > 512) G = 512;     // 2 blocks/CU; G=1024 measured -8.3us worse (R11)
  G &= ~(SL_ - 1);
  if (G < SL_) G = SL_;

  float* couter         = (float*)d_ws;
  unsigned short* Spart = (unsigned short*)(couter + 16384);
  float* Zpart          = (float*)(Spart + (size_t)B_ * G * K_);

  k1_cueproj<<<dim3(B_), dim3(256), 0, stream>>>(cue, wcue, couter);
  k2_attend<<<dim3(G), dim3(256), 0, stream>>>(slot, prio, couter, Spart,
                                               Zpart, G);
  k3_fused<<<dim3(B_), dim3(256), 0, stream>>>(Spart, Zpart, wdec, out, G);
}